// Round 13
// baseline (160.956 us; speedup 1.0000x reference)
//
#include <hip/hip_runtime.h>
#include <hip/hip_bf16.h>
#include <math.h>

// Problem sizes (fixed by reference)
static constexpr int Bn = 16, Sn = 512, Wn = 8, Dn = 768;
static constexpr int Mn_ = 2, WMn = 64;
static constexpr int Un = 32, WUn = 16;

#define INF_VAL 1e12f
#define INV_SQRT_D 0.03608439182435161f

// Output float offsets
static constexpr size_t OFF_GCN   = 0;                    // [16,512,768]
static constexpr size_t OFF_MASK  = 6291456;              // [16,512,1]
static constexpr size_t OFF_DENSE = 6299648;              // [16,512,512]
static constexpr size_t OFF_ADJ   = 10493952;             // [16,512,512]
static constexpr size_t OFF_MAIN  = 14688256;             // [16,2,768]
static constexpr size_t OFF_USER  = 14712832;             // [16,768]

// Workspace byte offsets (~61 MB total; ws is ~393 MB)
static constexpr size_t WSB_GBF     = 0;          // bf16 [8192][768]
static constexpr size_t WSB_GT      = 12582912;   // bf16 [16][768][512]
static constexpr size_t WSB_DENSEBF = 25165824;   // bf16 [8192][512]
static constexpr size_t WSB_HBF     = 33554432;   // bf16 [8192][768]
static constexpr size_t WSB_KWT     = 46137344;   // bf16 [768][768]  (K_w^T)
static constexpr size_t WSB_QWT     = 47316992;   // bf16 [768][768]  (Q_w^T)
static constexpr size_t WSB_MT      = 48496640;   // bf16 [768][768]  (M^T)
static constexpr size_t WSB_PARTU   = 49676288;   // f32 [512][768]
static constexpr size_t WSB_PARTM   = 51249152;   // f32 [128][768]
static constexpr size_t WSB_KBAR    = 51642368;   // f64 [768]
static constexpr size_t WSB_QBAR    = 51648512;   // f64 [768]
static constexpr size_t WSB_U       = 51654656;   // f64 [768]
static constexpr size_t WSB_V       = 51660800;   // f64 [768]
static constexpr size_t WSB_VA      = 51666944;   // f64 [768]
static constexpr size_t WSB_VB      = 51673088;   // f64 [768]
static constexpr size_t WSB_CONSTS  = 51679232;   // f64 [4]
static constexpr size_t WSB_QS      = 51679296;   // f32 [8192]
static constexpr size_t WSB_KQ      = 51712064;   // f32 [8192]
static constexpr size_t WSB_GA      = 51744832;   // f32 [8192]
static constexpr size_t WSB_GB      = 51777600;   // f32 [8192]
static constexpr size_t WSB_COLSUM  = 51810368;   // f32 [8192]
static constexpr size_t WSB_FLAGS   = 51843136;   // int [8192]
static constexpr size_t WSB_ROWSUM  = 51875904;   // f32 [8192]
static constexpr size_t WSB_UVU     = 51908672;   // f64 [8][768]
static constexpr size_t WSB_UVV     = 51957824;   // f64 [8][768]
static constexpr size_t WSB_UVA     = 52006976;   // f64 [8][768]
static constexpr size_t WSB_UVB     = 52056128;   // f64 [8][768]

typedef __attribute__((ext_vector_type(8))) short short8;
typedef __attribute__((ext_vector_type(4))) float f32x4;

static __device__ __forceinline__ ushort f2bf(float f) {
    union { float f; unsigned u; } v; v.f = f;
    unsigned u = v.u;
    unsigned r = (u + 0x7FFFu + ((u >> 16) & 1u)) >> 16;
    return (ushort)r;
}

static __device__ __forceinline__ void gload16(const void* g, void* lds) {
    __builtin_amdgcn_global_load_lds(
        (const __attribute__((address_space(1))) void*)g,
        (__attribute__((address_space(3))) void*)lds, 16, 0, 0);
}

static __device__ __forceinline__ void fmax4(float4& a, const float4& x) {
    a.x = fmaxf(a.x, x.x); a.y = fmaxf(a.y, x.y);
    a.z = fmaxf(a.z, x.z); a.w = fmaxf(a.w, x.w);
}

// ---------------------------------------------------------------------------
// fold1: blocks 0..191 kbar/qbar row sums; 192..1343 transpose-convert
// K_w->KwbT, Q_w->QwbT (bf16, [i][e]); 1344 colsum zero.
__global__ __launch_bounds__(256)
void fold1(const float* __restrict__ K_w, const float* __restrict__ K_b,
           const float* __restrict__ Q_w, const float* __restrict__ Q_b,
           double* __restrict__ kbar, double* __restrict__ qbar,
           ushort* __restrict__ KwbT, ushort* __restrict__ QwbT,
           float* __restrict__ colsum) {
    int blk = blockIdx.x, t = threadIdx.x;
    if (blk < 192) {
        int wv = t >> 6, lane = t & 63;
        int r = blk * 4 + wv;
        double sk = 0.0, sq = 0.0;
        for (int d = lane; d < Dn; d += 64) {
            sk += (double)K_w[(size_t)r * Dn + d];
            sq += (double)Q_w[(size_t)r * Dn + d];
        }
        #pragma unroll
        for (int off = 32; off > 0; off >>= 1) {
            sk += __shfl_down(sk, off, 64);
            sq += __shfl_down(sq, off, 64);
        }
        if (lane == 0) {
            kbar[r] = -1e12 * sk + (double)K_b[r];
            qbar[r] = -1e12 * sq + (double)Q_b[r];
        }
    } else if (blk < 1344) {
        int tt = blk - 192;                         // 0..1151
        const float* src = (tt < 576) ? K_w : Q_w;
        ushort* dst = (tt < 576) ? KwbT : QwbT;
        int t6 = (tt < 576) ? tt : tt - 576;
        int e0 = (t6 % 24) * 32, i0 = (t6 / 24) * 32;
        __shared__ ushort tile[32][33];
        int tx = t & 31, ty = t >> 5;
        #pragma unroll
        for (int i2 = 0; i2 < 4; ++i2)
            tile[ty + i2 * 8][tx] = f2bf(src[(size_t)(e0 + ty + i2 * 8) * Dn + i0 + tx]);
        __syncthreads();
        #pragma unroll
        for (int i2 = 0; i2 < 4; ++i2)
            dst[(size_t)(i0 + ty + i2 * 8) * Dn + e0 + tx] = tile[tx][ty + i2 * 8];
    } else {
        for (int i = t; i < Bn * Sn; i += 256) colsum[i] = 0.f;
    }
}

// ---------------------------------------------------------------------------
// shared GEMM body (256 threads): 64x64 tile, BK=128, 32 KB LDS.
template<int OUT_BF16>
static __device__ __forceinline__
void gemm_device(const ushort* __restrict__ A, const ushort* __restrict__ B,
                 void* __restrict__ Cout, int bx, int by, int bz,
                 int Km, int lda, int ldb, int ldc,
                 long long sA, long long sB, long long sC,
                 ushort* As, ushort* Bs) {
    const ushort* Ab = A + (size_t)bz * sA;
    const ushort* Bb = B + (size_t)bz * sB;
    int i0 = by * 64, j0 = bx * 64;
    int tid = threadIdx.x;
    int lane = tid & 63, wv = tid >> 6;
    int wr = wv >> 1, wc = wv & 1;
    int ln15 = lane & 15, lkg = lane >> 4;
    int r4 = lane >> 4;       // row within 4-row group
    int c16 = lane & 15;      // 16B chunk index

    f32x4 acc[2][2] = {};

    for (int k0 = 0; k0 < Km; k0 += 128) {
        #pragma unroll
        for (int it = 0; it < 4; ++it) {
            int r = it * 16 + wv * 4 + r4;
            int cc = c16 ^ (r & 15);
            ushort* dstA = As + (it * 4096 + wv * 1024) / 2;   // wave-uniform
            gload16(Ab + (size_t)(i0 + r) * lda + k0 + cc * 8, dstA);
        }
        #pragma unroll
        for (int it = 0; it < 4; ++it) {
            int r = it * 16 + wv * 4 + r4;
            int cc = c16 ^ (r & 15);
            ushort* dstB = Bs + (it * 4096 + wv * 1024) / 2;
            gload16(Bb + (size_t)(j0 + r) * ldb + k0 + cc * 8, dstB);
        }
        __syncthreads();
        #pragma unroll
        for (int kh = 0; kh < 4; ++kh) {
            short8 af[2], bfr[2];
            int kc = kh * 4 + lkg;
            #pragma unroll
            for (int f = 0; f < 2; ++f) {
                int ra = wr * 32 + f * 16 + ln15;
                af[f] = *(const short8*)((const char*)As + ra * 256 + ((kc ^ (ra & 15)) << 4));
                int rb = wc * 32 + f * 16 + ln15;
                bfr[f] = *(const short8*)((const char*)Bs + rb * 256 + ((kc ^ (rb & 15)) << 4));
            }
            #pragma unroll
            for (int fa = 0; fa < 2; ++fa)
                #pragma unroll
                for (int fb = 0; fb < 2; ++fb)
                    acc[fa][fb] = __builtin_amdgcn_mfma_f32_16x16x32_bf16(
                        af[fa], bfr[fb], acc[fa][fb], 0, 0, 0);
        }
        __syncthreads();
    }

    #pragma unroll
    for (int fa = 0; fa < 2; ++fa) {
        #pragma unroll
        for (int fb = 0; fb < 2; ++fb) {
            int n = j0 + wc * 32 + fb * 16 + ln15;
            #pragma unroll
            for (int rr = 0; rr < 4; ++rr) {
                int m = i0 + wr * 32 + fa * 16 + lkg * 4 + rr;
                float val = acc[fa][fb][rr];
                if (OUT_BF16) {
                    ((ushort*)Cout)[(size_t)bz * sC + (size_t)m * ldc + n] = f2bf(val);
                } else {
                    ((float*)Cout)[(size_t)bz * sC + (size_t)m * ldc + n] = val;
                }
            }
        }
    }
}

// standalone GEMM kernel
template<int OUT_BF16>
__global__ __launch_bounds__(256)
void gemm_mfma(const ushort* __restrict__ A, const ushort* __restrict__ B,
               void* __restrict__ Cout,
               int Km, int lda, int ldb, int ldc,
               long long sA, long long sB, long long sC) {
    __shared__ ushort As[64 * 128];
    __shared__ ushort Bs[64 * 128];
    gemm_device<OUT_BF16>(A, B, Cout, blockIdx.x, blockIdx.y, blockIdx.z,
                          Km, lda, ldb, ldc, sA, sB, sC, As, Bs);
}

// ---------------------------------------------------------------------------
// Merged (256 thr): blocks 0..23 u/v/a/b fold partials; 24..167 Mt GEMM;
// 168..679 adj softmax (LDS-staged) + rowsum + colsum partials.
__global__ __launch_bounds__(256)
void adjuvmt_kernel(const float* __restrict__ adj, float* __restrict__ adjsm,
                    float* __restrict__ colsum, float* __restrict__ rowsum,
                    const float* __restrict__ K_w, const float* __restrict__ Q_w,
                    const float* __restrict__ K_b, const float* __restrict__ Q_b,
                    const double* __restrict__ kbar, const double* __restrict__ qbar,
                    double* __restrict__ uvu, double* __restrict__ uvv,
                    double* __restrict__ uva, double* __restrict__ uvb,
                    const ushort* __restrict__ QwbT, const ushort* __restrict__ KwbT,
                    ushort* __restrict__ Mt) {
    __shared__ ushort SB[16384];       // 32 KB: GEMM As+Bs, or adjsm row stage
    __shared__ float n1s[16];
    int blk = blockIdx.x;
    int t = threadIdx.x;
    if (blk < 24) {
        int id = blk * 256 + t;        // 0..6143 = 8 chunks x 768 j
        int c = id / 768;
        int j = id - c * 768;
        int e0 = c * 96;
        double su = 0.0, sv = 0.0, sa = 0.0, sb = 0.0;
        for (int e = e0; e < e0 + 96; ++e) {
            double kw = (double)K_w[(size_t)e * Dn + j];
            double qw = (double)Q_w[(size_t)e * Dn + j];
            su += kw * qbar[e];
            sv += qw * kbar[e];
            sa += kw * (double)Q_b[e];
            sb += qw * (double)K_b[e];
        }
        uvu[(size_t)c * Dn + j] = su;
        uvv[(size_t)c * Dn + j] = sv;
        uva[(size_t)c * Dn + j] = sa;
        uvb[(size_t)c * Dn + j] = sb;
        return;
    }
    if (blk < 168) {
        int g = blk - 24;              // 144 blocks: 12x12 tiles
        gemm_device<1>(QwbT, KwbT, Mt, g % 12, g / 12, 0,
                       Dn, Dn, Dn, Dn, 0, 0, 0, SB, SB + 8192);
        return;
    }
    int ab = blk - 168;                // 0..511
    int b = ab >> 5, rc = ab & 31;
    const float* base = adj + ((size_t)b * Sn + rc * 16) * Sn;
    float* obase = adjsm + ((size_t)b * Sn + rc * 16) * Sn;
    const float EM1 = 0.36787944117144233f;   // exp(-1)
    const float EP1 = 2.718281828459045f;     // exp(+1)
    float (*rows)[512] = (float(*)[512])SB;   // 16*512*4 = 32 KB
    // stage 16 rows (2 cols per thread)
    #pragma unroll
    for (int r = 0; r < 16; ++r) {
        rows[r][t]       = base[(size_t)r * Sn + t];
        rows[r][t + 256] = base[(size_t)r * Sn + t + 256];
    }
    __syncthreads();
    // per-wave rowsums: wave w handles rows 4w..4w+3 (exact integer sums)
    int wv = t >> 6, lane = t & 63;
    #pragma unroll
    for (int rr2 = 0; rr2 < 4; ++rr2) {
        int r = wv * 4 + rr2;
        float s = 0.f;
        #pragma unroll
        for (int c = 0; c < 8; ++c) s += rows[r][lane + c * 64];
        #pragma unroll
        for (int off = 32; off > 0; off >>= 1) s += __shfl_down(s, off, 64);
        if (lane == 0) {
            n1s[r] = s;
            rowsum[(size_t)b * Sn + rc * 16 + r] = s;
        }
    }
    __syncthreads();
    float colacc0 = 0.f, colacc1 = 0.f;
    #pragma unroll
    for (int r = 0; r < 16; ++r) {
        float a0 = rows[r][t], a1 = rows[r][t + 256];
        colacc0 += a0; colacc1 += a1;
        float n1 = n1s[r];
        float e1, e0;
        if (n1 > 0.f) { e1 = 1.f; e0 = EM1; } else { e1 = EP1; e0 = 1.f; }
        float inv = 1.f / (n1 * e1 + (512.f - n1) * e0);
        obase[(size_t)r * Sn + t]       = (a0 == 1.f ? e1 : e0) * inv;
        obase[(size_t)r * Sn + t + 256] = (a1 == 1.f ? e1 : e0) * inv;
    }
    atomicAdd(&colsum[(size_t)b * Sn + t], colacc0);
    atomicAdd(&colsum[(size_t)b * Sn + t + 256], colacc1);
}

// blocks 0..11: reduce u/v/a/b (64 thr); block 12: consts c0..c3
__global__ __launch_bounds__(64)
void uvred_consts(const double* __restrict__ uvu, const double* __restrict__ uvv,
                  const double* __restrict__ uva, const double* __restrict__ uvb,
                  const double* __restrict__ kbar, const double* __restrict__ qbar,
                  const float* __restrict__ K_b, const float* __restrict__ Q_b,
                  double* __restrict__ u, double* __restrict__ v,
                  double* __restrict__ va, double* __restrict__ vb,
                  double* __restrict__ consts) {
    int blk = blockIdx.x;
    int l = threadIdx.x;
    if (blk < 12) {
        int j = blk * 64 + l;
        double su = 0.0, sv = 0.0, sa = 0.0, sb = 0.0;
        #pragma unroll
        for (int c = 0; c < 8; ++c) {
            su += uvu[(size_t)c * Dn + j];
            sv += uvv[(size_t)c * Dn + j];
            sa += uva[(size_t)c * Dn + j];
            sb += uvb[(size_t)c * Dn + j];
        }
        u[j] = su; v[j] = sv; va[j] = sa; vb[j] = sb;
    } else {
        double c0 = 0.0, c1 = 0.0, c2 = 0.0, c3 = 0.0;
        for (int e = l; e < Dn; e += 64) {
            c0 += kbar[e] * (double)Q_b[e];
            c1 += kbar[e] * qbar[e];
            c2 += qbar[e] * (double)K_b[e];
            c3 += (double)K_b[e] * (double)Q_b[e];
        }
        #pragma unroll
        for (int off = 32; off > 0; off >>= 1) {
            c0 += __shfl_down(c0, off, 64);
            c1 += __shfl_down(c1, off, 64);
            c2 += __shfl_down(c2, off, 64);
            c3 += __shfl_down(c3, off, 64);
        }
        if (l == 0) { consts[0] = c0; consts[1] = c1; consts[2] = c2; consts[3] = c3; }
    }
}

// ---------------------------------------------------------------------------
// merged: blocks 0..8191 = g pool (+f64 dots); 8192..8319 main s1; 8320..8831 user s1
__global__ __launch_bounds__(192)
void pool_g_s1(const int* __restrict__ words, const int* __restrict__ masks,
               const int* __restrict__ main_idx, const int* __restrict__ mmask,
               const int* __restrict__ user_idx, const int* __restrict__ umask,
               const float* __restrict__ emb,
               const double* __restrict__ u, const double* __restrict__ v,
               const double* __restrict__ va, const double* __restrict__ vb,
               const double* __restrict__ consts,
               ushort* __restrict__ gbf, float* __restrict__ qs,
               float* __restrict__ kq, float* __restrict__ ga,
               float* __restrict__ gb, int* __restrict__ flags,
               float* __restrict__ partM, float* __restrict__ partU) {
    int blk = blockIdx.x;
    int t = threadIdx.x;
    if (blk >= Bn * Sn) {
        int s1 = blk - Bn * Sn;
        const int *irow, *mrow;
        float* dst;
        if (s1 < 128) {
            int bm = s1 >> 2, ch = s1 & 3;
            irow = main_idx + (size_t)bm * WMn + ch * 16;
            mrow = mmask + (size_t)bm * WMn + ch * 16;
            dst = partM + (size_t)s1 * Dn;
        } else {
            int bu = s1 - 128;
            irow = user_idx + (size_t)bu * WUn;
            mrow = umask + (size_t)bu * WUn;
            dst = partU + (size_t)bu * Dn;
        }
        float4 acc = make_float4(-INF_VAL, -INF_VAL, -INF_VAL, -INF_VAL);
        #pragma unroll
        for (int w = 0; w < 16; ++w) {
            if (mrow[w] != 0) continue;
            float4 x = ((const float4*)(emb + (size_t)irow[w] * Dn))[t];
            fmax4(acc, x);
        }
        ((float4*)dst)[t] = acc;
        return;
    }
    int bs = blk;
    const int* wrow = words + (size_t)bs * Wn;
    const int* mrow = masks + (size_t)bs * Wn;
    float4 acc = make_float4(-INF_VAL, -INF_VAL, -INF_VAL, -INF_VAL);
    int nm = 0;
    #pragma unroll
    for (int w = 0; w < Wn; ++w) {
        int mk = mrow[w];
        nm += (mk != 0);
        if (mk != 0) continue;
        float4 x = ((const float4*)(emb + (size_t)wrow[w] * Dn))[t];
        fmax4(acc, x);
    }
    ushort4 o;
    o.x = f2bf(acc.x); o.y = f2bf(acc.y); o.z = f2bf(acc.z); o.w = f2bf(acc.w);
    ((ushort4*)(gbf + (size_t)bs * Dn))[t] = o;
    int j = t * 4;
    double dv = v[j] * (double)acc.x + v[j+1] * (double)acc.y
              + v[j+2] * (double)acc.z + v[j+3] * (double)acc.w;
    double du = u[j] * (double)acc.x + u[j+1] * (double)acc.y
              + u[j+2] * (double)acc.z + u[j+3] * (double)acc.w;
    double da = va[j] * (double)acc.x + va[j+1] * (double)acc.y
              + va[j+2] * (double)acc.z + va[j+3] * (double)acc.w;
    double db = vb[j] * (double)acc.x + vb[j+1] * (double)acc.y
              + vb[j+2] * (double)acc.z + vb[j+3] * (double)acc.w;
    #pragma unroll
    for (int off = 32; off > 0; off >>= 1) {
        dv += __shfl_down(dv, off, 64);
        du += __shfl_down(du, off, 64);
        da += __shfl_down(da, off, 64);
        db += __shfl_down(db, off, 64);
    }
    __shared__ double rr[12];
    if ((t & 63) == 0) {
        rr[t >> 6] = dv; rr[3 + (t >> 6)] = du;
        rr[6 + (t >> 6)] = da; rr[9 + (t >> 6)] = db;
    }
    __syncthreads();
    if (t == 0) {
        qs[bs] = (float)(rr[0] + rr[1] + rr[2] + consts[0]);
        kq[bs] = (float)(rr[3] + rr[4] + rr[5] + consts[2]);
        ga[bs] = (float)(rr[6] + rr[7] + rr[8]);
        gb[bs] = (float)(rr[9] + rr[10] + rr[11]);
        flags[bs] = (nm == Wn) ? 1 : 0;
    }
}

// ---------------------------------------------------------------------------
// midh: blocks 0..1535 = h GEMM (critical path first); 1536..7679 transpose;
// 7680..7711 main s2; 7712..7727 user s2; 7728..7759 node mask.
__global__ __launch_bounds__(256)
void midh_kernel(const ushort* __restrict__ gbf, const ushort* __restrict__ Mt,
                 ushort* __restrict__ hbf, ushort* __restrict__ gT,
                 const float* __restrict__ partM, const float* __restrict__ partU,
                 float* __restrict__ outM, float* __restrict__ outU,
                 const float* __restrict__ rowsum, const float* __restrict__ colsum,
                 float* __restrict__ maskout) {
    __shared__ ushort SB[16384];       // 32 KB
    int blk = blockIdx.x;
    int t = threadIdx.x;
    if (blk < 1536) {
        gemm_device<1>(gbf, Mt, hbf, blk % 12, blk / 12, 0,
                       Dn, Dn, Dn, Dn, 0, 0, 0, SB, SB + 8192);
        return;
    }
    if (blk < 7680) {
        int bb = blk - 1536;
        ushort (*tile)[33] = (ushort(*)[33])SB;    // reuse GEMM LDS
        int b = bb / 384;
        int rem = bb - b * 384;
        int d0 = (rem % 24) * 32, s0 = (rem / 24) * 32;
        int tx = t & 31, ty = t >> 5;
        #pragma unroll
        for (int i = 0; i < 4; ++i)
            tile[ty + i * 8][tx] = gbf[((size_t)(b * Sn + s0 + ty + i * 8)) * Dn + d0 + tx];
        __syncthreads();
        #pragma unroll
        for (int i = 0; i < 4; ++i)
            gT[((size_t)(b * Dn + d0 + ty + i * 8)) * Sn + s0 + tx] = tile[tx][ty + i * 8];
        return;
    }
    if (blk >= 7728) {
        int i = (blk - 7728) * 256 + t;
        if (i < Bn * Sn)
            maskout[i] = ((rowsum[i] + colsum[i]) == 0.f) ? 1.f : 0.f;
        return;
    }
    if (t >= 192) return;
    float4 acc = make_float4(-INF_VAL, -INF_VAL, -INF_VAL, -INF_VAL);
    float* dst;
    if (blk < 7712) {
        int bm = blk - 7680;
        #pragma unroll
        for (int c = 0; c < 4; ++c) {
            float4 x = ((const float4*)(partM + (size_t)(bm * 4 + c) * Dn))[t];
            fmax4(acc, x);
        }
        dst = outM + (size_t)bm * Dn;
    } else {
        int b = blk - 7712;
        for (int u2 = 0; u2 < Un; ++u2) {
            float4 x = ((const float4*)(partU + (size_t)(b * Un + u2) * Dn))[t];
            fmax4(acc, x);
        }
        dst = outU + (size_t)b * Dn;
    }
    if (acc.x == -INF_VAL) acc.x = 0.f;
    if (acc.y == -INF_VAL) acc.y = 0.f;
    if (acc.z == -INF_VAL) acc.z = 0.f;
    if (acc.w == -INF_VAL) acc.w = 0.f;
    ((float4*)dst)[t] = acc;
}

// ---------------------------------------------------------------------------
// Fused scores GEMM + fixup + softmax. Block (ms, b) computes a 16x512 slab:
// S[r0+m][n] = h[b][r0+m] . g[b][n], then masked fixup + row softmax.
// A (h-panel, 16x768) staged once in LDS (chunk-XOR swizzle); B (g[b]) streamed
// from global/L2 as direct MFMA B-fragments. NO barriers in the k-loop.
// C layout (verified m89): col = lane&15 (+16*nf+128*wv), row = (lane>>4)*4+rr.
__global__ __launch_bounds__(256)
void scoresm_kernel(const ushort* __restrict__ hbf, const ushort* __restrict__ gbf,
                    const int* __restrict__ flags, const float* __restrict__ qs,
                    const float* __restrict__ kq, const float* __restrict__ ga,
                    const float* __restrict__ gb, const double* __restrict__ consts,
                    float* __restrict__ dense, ushort* __restrict__ densebf) {
    __shared__ ushort As[16 * 768];    // 24 KB
    __shared__ float smax[4][16];
    __shared__ float ssum[4][16];
    int b = blockIdx.y;
    int r0 = blockIdx.x * 16;
    int t = threadIdx.x;
    int lane = t & 63, wv = t >> 6;
    int ln15 = lane & 15, lkg = lane >> 4;

    // stage A: rows r0..r0+15 of h[b]; chunk c of row r stored at chunk c^(r) (low4)
    const ushort* Ab = hbf + ((size_t)b * Sn + r0) * Dn;
    for (int i = t; i < 1536; i += 256) {
        int r = i / 96, c = i - (i / 96) * 96;
        int cs = (c & ~15) | ((c & 15) ^ r);
        *(short8*)((char*)As + (r * 96 + cs) * 16) =
            *(const short8*)((const char*)Ab + (size_t)r * Dn * 2 + c * 16);
    }
    __syncthreads();

    // k-loop: 24 steps x 8 B-frags/wave; A from LDS, B direct from global (L2)
    const ushort* Bb = gbf + (size_t)b * Sn * Dn;
    f32x4 acc[8] = {};
    for (int s = 0; s < 24; ++s) {
        int kc = s * 4 + lkg;          // 16B-chunk index 0..95
        int cs = (kc & ~15) | ((kc & 15) ^ ln15);
        short8 af = *(const short8*)((char*)As + (ln15 * 96 + cs) * 16);
        #pragma unroll
        for (int nf = 0; nf < 8; ++nf) {
            int n = wv * 128 + nf * 16 + ln15;
            short8 bf = *(const short8*)((const char*)Bb + ((size_t)n * Dn + kc * 8) * 2);
            acc[nf] = __builtin_amdgcn_mfma_f32_16x16x32_bf16(af, bf, acc[nf], 0, 0, 0);
        }
    }

    // fixup into x-values (in-place in acc)
    float c1v = (float)consts[1] * INV_SQRT_D;
    float c3v = (float)consts[3];
    int rowflag[4]; float kqv[4], gav[4];
    #pragma unroll
    for (int rr2 = 0; rr2 < 4; ++rr2) {
        int row = (b << 9) + r0 + lkg * 4 + rr2;
        rowflag[rr2] = flags[row];
        kqv[rr2] = kq[row] * INV_SQRT_D;
        gav[rr2] = ga[row] + c3v;
    }
    #pragma unroll
    for (int nf = 0; nf < 8; ++nf) {
        int col = wv * 128 + nf * 16 + ln15;
        int fcol = flags[(b << 9) + col];
        float qscol = qs[(b << 9) + col] * INV_SQRT_D;
        float gbcol = gb[(b << 9) + col];
        #pragma unroll
        for (int rr2 = 0; rr2 < 4; ++rr2) {
            float x;
            if (rowflag[rr2]) {
                x = fcol ? c1v : qscol;
            } else {
                x = fcol ? kqv[rr2]
                         : (acc[nf][rr2] + gav[rr2] + gbcol) * INV_SQRT_D;
            }
            acc[nf][rr2] = x;
        }
    }

    // row max: in-lane over nf, butterfly over ln15, LDS combine over waves
    float mx[4];
    #pragma unroll
    for (int rr2 = 0; rr2 < 4; ++rr2) {
        float m = acc[0][rr2];
        #pragma unroll
        for (int nf = 1; nf < 8; ++nf) m = fmaxf(m, acc[nf][rr2]);
        #pragma unroll
        for (int msk = 1; msk < 16; msk <<= 1) m = fmaxf(m, __shfl_xor(m, msk, 64));
        mx[rr2] = m;
        if (ln15 == 0) smax[wv][lkg * 4 + rr2] = m;
    }
    __syncthreads();
    #pragma unroll
    for (int rr2 = 0; rr2 < 4; ++rr2) {
        int m_ = lkg * 4 + rr2;
        mx[rr2] = fmaxf(fmaxf(smax[0][m_], smax[1][m_]),
                        fmaxf(smax[2][m_], smax[3][m_]));
    }

    // exp + row sum
    float sm[4] = {0.f, 0.f, 0.f, 0.f};
    #pragma unroll
    for (int nf = 0; nf < 8; ++nf)
        #pragma unroll
        for (int rr2 = 0; rr2 < 4; ++rr2) {
            float e = expf(acc[nf][rr2] - mx[rr2]);
            acc[nf][rr2] = e;
            sm[rr2] += e;
        }
    #pragma unroll
    for (int rr2 = 0; rr2 < 4; ++rr2) {
        float s2 = sm[rr2];
        #pragma unroll
        for (int msk = 1; msk < 16; msk <<= 1) s2 += __shfl_xor(s2, msk, 64);
        if (ln15 == 0) ssum[wv][lkg * 4 + rr2] = s2;
    }
    __syncthreads();
    float inv[4];
    #pragma unroll
    for (int rr2 = 0; rr2 < 4; ++rr2) {
        int m_ = lkg * 4 + rr2;
        inv[rr2] = 1.f / (ssum[0][m_] + ssum[1][m_] + ssum[2][m_] + ssum[3][m_]);
    }

    // write dense f32 + densebf bf16
    #pragma unroll
    for (int nf = 0; nf < 8; ++nf) {
        int col = wv * 128 + nf * 16 + ln15;
        #pragma unroll
        for (int rr2 = 0; rr2 < 4; ++rr2) {
            size_t rowg = (size_t)(b << 9) + r0 + lkg * 4 + rr2;
            float p = acc[nf][rr2] * inv[rr2];
            dense[rowg * 512 + col] = p;
            densebf[rowg * 512 + col] = f2bf(p);
        }
    }
}

// ---------------------------------------------------------------------------
extern "C" void kernel_launch(void* const* d_in, const int* in_sizes, int n_in,
                              void* d_out, int out_size, void* d_ws, size_t ws_size,
                              hipStream_t stream) {
    const int*   words     = (const int*)d_in[0];
    const int*   masks     = (const int*)d_in[1];
    const int*   main_idx  = (const int*)d_in[2];
    const int*   main_mask = (const int*)d_in[3];
    const int*   user_idx  = (const int*)d_in[4];
    const int*   user_mask = (const int*)d_in[5];
    const float* adj       = (const float*)d_in[6];
    const float* emb       = (const float*)d_in[7];
    const float* K_w       = (const float*)d_in[8];
    const float* K_b       = (const float*)d_in[9];
    const float* Q_w       = (const float*)d_in[10];
    const float* Q_b       = (const float*)d_in[11];

    float* out = (float*)d_out;
    char*  ws8 = (char*)d_ws;

    ushort* gbf     = (ushort*)(ws8 + WSB_GBF);
    ushort* gT      = (ushort*)(ws8 + WSB_GT);
    ushort* densebf = (ushort*)(ws8 + WSB_DENSEBF);
    ushort* hbf     = (ushort*)(ws8 + WSB_HBF);
    ushort* KwbT    = (ushort*)(ws8 + WSB_KWT);
    ushort* QwbT    = (ushort*)(ws8 + WSB_QWT);
    ushort* Mt      = (ushort*)(ws8 + WSB_MT);
    float*  partU   = (float*)(ws8 + WSB_PARTU);
    float*  partM   = (float*)(ws8 + WSB_PARTM);
    double* kbar    = (double*)(ws8 + WSB_KBAR);
    double* qbar    = (double*)(ws8 + WSB_QBAR);
    double* u       = (double*)(ws8 + WSB_U);
    double* v       = (double*)(ws8 + WSB_V);
    double* va      = (double*)(ws8 + WSB_VA);
    double* vb      = (double*)(ws8 + WSB_VB);
    double* consts  = (double*)(ws8 + WSB_CONSTS);
    float*  qs      = (float*)(ws8 + WSB_QS);
    float*  kq      = (float*)(ws8 + WSB_KQ);
    float*  ga      = (float*)(ws8 + WSB_GA);
    float*  gb      = (float*)(ws8 + WSB_GB);
    float*  colsum  = (float*)(ws8 + WSB_COLSUM);
    int*    flags   = (int*)(ws8 + WSB_FLAGS);
    float*  rowsum  = (float*)(ws8 + WSB_ROWSUM);
    double* uvu     = (double*)(ws8 + WSB_UVU);
    double* uvv     = (double*)(ws8 + WSB_UVV);
    double* uva     = (double*)(ws8 + WSB_UVA);
    double* uvb     = (double*)(ws8 + WSB_UVB);

    float* dense = out + OFF_DENSE;

    // 1: weight row-sums + transposed bf16 converts + colsum zero
    fold1<<<1345, 256, 0, stream>>>(K_w, K_b, Q_w, Q_b, kbar, qbar, KwbT, QwbT, colsum);

    // 2: u/v/a/b partials ∥ Mt GEMM (144 blocks) ∥ adj softmax (merged)
    adjuvmt_kernel<<<680, 256, 0, stream>>>(adj, out + OFF_ADJ, colsum, rowsum,
                                            K_w, Q_w, K_b, Q_b, kbar, qbar,
                                            uvu, uvv, uva, uvb, QwbT, KwbT, Mt);

    // 3: reduce u/v/a/b + consts (tiny)
    uvred_consts<<<13, 64, 0, stream>>>(uvu, uvv, uva, uvb, kbar, qbar, K_b, Q_b,
                                        u, v, va, vb, consts);

    // 4: pools (g + s1 merged)
    pool_g_s1<<<Bn * Sn + 640, 192, 0, stream>>>(
        words, masks, main_idx, main_mask, user_idx, user_mask, emb,
        u, v, va, vb, consts, gbf, qs, kq, ga, gb, flags, partM, partU);

    // 5: h GEMM (1536 blocks) ∥ transpose g ∥ pool stage2 ∥ node mask (merged)
    midh_kernel<<<7760, 256, 0, stream>>>(gbf, Mt, hbf, gT, partM, partU,
                                          out + OFF_MAIN, out + OFF_USER,
                                          rowsum, colsum, out + OFF_MASK);

    // 6: fused scores GEMM + fixup + softmax (barrier-free k-loop)
    scoresm_kernel<<<dim3(32, Bn), 256, 0, stream>>>(
        hbf, gbf, flags, qs, kq, ga, gb, consts, dense, densebf);

    // 7: gcn[b] = P[b] @ g[b]  (1536 blocks, 6/CU)
    gemm_mfma<0><<<dim3(12, 8, Bn), 256, 0, stream>>>(
        densebf, gT, out + OFF_GCN, Sn, Sn, Sn, Dn,
        (long long)Sn * Sn, (long long)Dn * Sn, (long long)Sn * Dn);
}

// Round 14
// 137.557 us; speedup vs baseline: 1.1701x; 1.1701x over previous
//
#include <hip/hip_runtime.h>
#include <hip/hip_bf16.h>
#include <math.h>

// Problem sizes (fixed by reference)
static constexpr int Bn = 16, Sn = 512, Wn = 8, Dn = 768;
static constexpr int Mn_ = 2, WMn = 64;
static constexpr int Un = 32, WUn = 16;

#define INF_VAL 1e12f
#define INV_SQRT_D 0.03608439182435161f

// Output float offsets
static constexpr size_t OFF_GCN   = 0;                    // [16,512,768]
static constexpr size_t OFF_MASK  = 6291456;              // [16,512,1]
static constexpr size_t OFF_DENSE = 6299648;              // [16,512,512]
static constexpr size_t OFF_ADJ   = 10493952;             // [16,512,512]
static constexpr size_t OFF_MAIN  = 14688256;             // [16,2,768]
static constexpr size_t OFF_USER  = 14712832;             // [16,768]

// Workspace byte offsets (~61 MB total; ws is ~393 MB)
static constexpr size_t WSB_GBF     = 0;          // bf16 [8192][768]
static constexpr size_t WSB_GT      = 12582912;   // bf16 [16][768][512]
static constexpr size_t WSB_DENSEBF = 25165824;   // bf16 [8192][512]
static constexpr size_t WSB_HBF     = 33554432;   // bf16 [8192][768]
static constexpr size_t WSB_KWT     = 46137344;   // bf16 [768][768]  (K_w^T)
static constexpr size_t WSB_QWT     = 47316992;   // bf16 [768][768]  (Q_w^T)
static constexpr size_t WSB_MT      = 48496640;   // bf16 [768][768]  (M^T)
static constexpr size_t WSB_PARTU   = 49676288;   // f32 [512][768]
static constexpr size_t WSB_PARTM   = 51249152;   // f32 [128][768]
static constexpr size_t WSB_KBAR    = 51642368;   // f64 [768]
static constexpr size_t WSB_QBAR    = 51648512;   // f64 [768]
static constexpr size_t WSB_U       = 51654656;   // f64 [768]
static constexpr size_t WSB_V       = 51660800;   // f64 [768]
static constexpr size_t WSB_VA      = 51666944;   // f64 [768]
static constexpr size_t WSB_VB      = 51673088;   // f64 [768]
static constexpr size_t WSB_CONSTS  = 51679232;   // f64 [4]
static constexpr size_t WSB_QS      = 51679296;   // f32 [8192]
static constexpr size_t WSB_KQ      = 51712064;   // f32 [8192]
static constexpr size_t WSB_GA      = 51744832;   // f32 [8192]
static constexpr size_t WSB_GB      = 51777600;   // f32 [8192]
static constexpr size_t WSB_COLSUM  = 51810368;   // f32 [8192]
static constexpr size_t WSB_FLAGS   = 51843136;   // int [8192]
static constexpr size_t WSB_ROWSUM  = 51875904;   // f32 [8192]
static constexpr size_t WSB_RAWBF   = 52105280;   // bf16 [8192][512] raw scores

typedef __attribute__((ext_vector_type(8))) short short8;
typedef __attribute__((ext_vector_type(4))) float f32x4;

static __device__ __forceinline__ ushort f2bf(float f) {
    union { float f; unsigned u; } v; v.f = f;
    unsigned u = v.u;
    unsigned r = (u + 0x7FFFu + ((u >> 16) & 1u)) >> 16;
    return (ushort)r;
}

static __device__ __forceinline__ float bf2f(unsigned hi16) {
    union { unsigned u; float f; } v; v.u = hi16 << 16; return v.f;
}

static __device__ __forceinline__ void gload16(const void* g, void* lds) {
    __builtin_amdgcn_global_load_lds(
        (const __attribute__((address_space(1))) void*)g,
        (__attribute__((address_space(3))) void*)lds, 16, 0, 0);
}

static __device__ __forceinline__ void fmax4(float4& a, const float4& x) {
    a.x = fmaxf(a.x, x.x); a.y = fmaxf(a.y, x.y);
    a.z = fmaxf(a.z, x.z); a.w = fmaxf(a.w, x.w);
}

// ---------------------------------------------------------------------------
// fold1: blocks 0..191 kbar/qbar row sums; 192..1343 transpose-convert
// K_w->KwbT, Q_w->QwbT; 1344 zeroes colsum + u/v/va/vb accumulators.
__global__ __launch_bounds__(256)
void fold1(const float* __restrict__ K_w, const float* __restrict__ K_b,
           const float* __restrict__ Q_w, const float* __restrict__ Q_b,
           double* __restrict__ kbar, double* __restrict__ qbar,
           ushort* __restrict__ KwbT, ushort* __restrict__ QwbT,
           float* __restrict__ colsum, double* __restrict__ uvzero) {
    int blk = blockIdx.x, t = threadIdx.x;
    if (blk < 192) {
        int wv = t >> 6, lane = t & 63;
        int r = blk * 4 + wv;
        double sk = 0.0, sq = 0.0;
        for (int d = lane; d < Dn; d += 64) {
            sk += (double)K_w[(size_t)r * Dn + d];
            sq += (double)Q_w[(size_t)r * Dn + d];
        }
        #pragma unroll
        for (int off = 32; off > 0; off >>= 1) {
            sk += __shfl_down(sk, off, 64);
            sq += __shfl_down(sq, off, 64);
        }
        if (lane == 0) {
            kbar[r] = -1e12 * sk + (double)K_b[r];
            qbar[r] = -1e12 * sq + (double)Q_b[r];
        }
    } else if (blk < 1344) {
        int tt = blk - 192;                         // 0..1151
        const float* src = (tt < 576) ? K_w : Q_w;
        ushort* dst = (tt < 576) ? KwbT : QwbT;
        int t6 = (tt < 576) ? tt : tt - 576;
        int e0 = (t6 % 24) * 32, i0 = (t6 / 24) * 32;
        __shared__ ushort tile[32][33];
        int tx = t & 31, ty = t >> 5;
        #pragma unroll
        for (int i2 = 0; i2 < 4; ++i2)
            tile[ty + i2 * 8][tx] = f2bf(src[(size_t)(e0 + ty + i2 * 8) * Dn + i0 + tx]);
        __syncthreads();
        #pragma unroll
        for (int i2 = 0; i2 < 4; ++i2)
            dst[(size_t)(i0 + ty + i2 * 8) * Dn + e0 + tx] = tile[tx][ty + i2 * 8];
    } else {
        for (int i = t; i < Bn * Sn; i += 256) colsum[i] = 0.f;
        for (int i = t; i < 4 * Dn; i += 256) uvzero[i] = 0.0;   // u,v,va,vb (contiguous)
    }
}

// ---------------------------------------------------------------------------
// shared GEMM body (256 threads): 64x64 tile, BK=128, 32 KB LDS.
template<int OUT_BF16>
static __device__ __forceinline__
void gemm_device(const ushort* __restrict__ A, const ushort* __restrict__ B,
                 void* __restrict__ Cout, int bx, int by, int bz,
                 int Km, int lda, int ldb, int ldc,
                 long long sA, long long sB, long long sC,
                 ushort* As, ushort* Bs) {
    const ushort* Ab = A + (size_t)bz * sA;
    const ushort* Bb = B + (size_t)bz * sB;
    int i0 = by * 64, j0 = bx * 64;
    int tid = threadIdx.x;
    int lane = tid & 63, wv = tid >> 6;
    int wr = wv >> 1, wc = wv & 1;
    int ln15 = lane & 15, lkg = lane >> 4;
    int r4 = lane >> 4;       // row within 4-row group
    int c16 = lane & 15;      // 16B chunk index

    f32x4 acc[2][2] = {};

    for (int k0 = 0; k0 < Km; k0 += 128) {
        #pragma unroll
        for (int it = 0; it < 4; ++it) {
            int r = it * 16 + wv * 4 + r4;
            int cc = c16 ^ (r & 15);
            ushort* dstA = As + (it * 4096 + wv * 1024) / 2;   // wave-uniform
            gload16(Ab + (size_t)(i0 + r) * lda + k0 + cc * 8, dstA);
        }
        #pragma unroll
        for (int it = 0; it < 4; ++it) {
            int r = it * 16 + wv * 4 + r4;
            int cc = c16 ^ (r & 15);
            ushort* dstB = Bs + (it * 4096 + wv * 1024) / 2;
            gload16(Bb + (size_t)(j0 + r) * ldb + k0 + cc * 8, dstB);
        }
        __syncthreads();
        #pragma unroll
        for (int kh = 0; kh < 4; ++kh) {
            short8 af[2], bfr[2];
            int kc = kh * 4 + lkg;
            #pragma unroll
            for (int f = 0; f < 2; ++f) {
                int ra = wr * 32 + f * 16 + ln15;
                af[f] = *(const short8*)((const char*)As + ra * 256 + ((kc ^ (ra & 15)) << 4));
                int rb = wc * 32 + f * 16 + ln15;
                bfr[f] = *(const short8*)((const char*)Bs + rb * 256 + ((kc ^ (rb & 15)) << 4));
            }
            #pragma unroll
            for (int fa = 0; fa < 2; ++fa)
                #pragma unroll
                for (int fb = 0; fb < 2; ++fb)
                    acc[fa][fb] = __builtin_amdgcn_mfma_f32_16x16x32_bf16(
                        af[fa], bfr[fb], acc[fa][fb], 0, 0, 0);
        }
        __syncthreads();
    }

    #pragma unroll
    for (int fa = 0; fa < 2; ++fa) {
        #pragma unroll
        for (int fb = 0; fb < 2; ++fb) {
            int n = j0 + wc * 32 + fb * 16 + ln15;
            #pragma unroll
            for (int rr = 0; rr < 4; ++rr) {
                int m = i0 + wr * 32 + fa * 16 + lkg * 4 + rr;
                float val = acc[fa][fb][rr];
                if (OUT_BF16) {
                    ((ushort*)Cout)[(size_t)bz * sC + (size_t)m * ldc + n] = f2bf(val);
                } else {
                    ((float*)Cout)[(size_t)bz * sC + (size_t)m * ldc + n] = val;
                }
            }
        }
    }
}

// standalone GEMM kernel
template<int OUT_BF16>
__global__ __launch_bounds__(256)
void gemm_mfma(const ushort* __restrict__ A, const ushort* __restrict__ B,
               void* __restrict__ Cout,
               int Km, int lda, int ldb, int ldc,
               long long sA, long long sB, long long sC) {
    __shared__ ushort As[64 * 128];
    __shared__ ushort Bs[64 * 128];
    gemm_device<OUT_BF16>(A, B, Cout, blockIdx.x, blockIdx.y, blockIdx.z,
                          Km, lda, ldb, ldc, sA, sB, sC, As, Bs);
}

// ---------------------------------------------------------------------------
// Merged (256 thr): blocks 0..23 u/v/a/b fold partials (f64 atomics into u/v);
// 24..167 Mt GEMM; 168..679 adj softmax + rowsum + colsum; 680 consts.
__global__ __launch_bounds__(256)
void adjuvmt_kernel(const float* __restrict__ adj, float* __restrict__ adjsm,
                    float* __restrict__ colsum, float* __restrict__ rowsum,
                    const float* __restrict__ K_w, const float* __restrict__ Q_w,
                    const float* __restrict__ K_b, const float* __restrict__ Q_b,
                    const double* __restrict__ kbar, const double* __restrict__ qbar,
                    double* __restrict__ u, double* __restrict__ v,
                    double* __restrict__ va, double* __restrict__ vb,
                    double* __restrict__ consts,
                    const ushort* __restrict__ QwbT, const ushort* __restrict__ KwbT,
                    ushort* __restrict__ Mt) {
    __shared__ ushort SB[16384];       // 32 KB: GEMM As+Bs, or adjsm row stage
    __shared__ float n1s[16];
    int blk = blockIdx.x;
    int t = threadIdx.x;
    if (blk < 24) {
        int id = blk * 256 + t;        // 0..6143 = 8 chunks x 768 j
        int c = id / 768;
        int j = id - c * 768;
        int e0 = c * 96;
        double su = 0.0, sv = 0.0, sa = 0.0, sb = 0.0;
        for (int e = e0; e < e0 + 96; ++e) {
            double kw = (double)K_w[(size_t)e * Dn + j];
            double qw = (double)Q_w[(size_t)e * Dn + j];
            su += kw * qbar[e];
            sv += qw * kbar[e];
            sa += kw * (double)Q_b[e];
            sb += qw * (double)K_b[e];
        }
        atomicAdd(&u[j], su);
        atomicAdd(&v[j], sv);
        atomicAdd(&va[j], sa);
        atomicAdd(&vb[j], sb);
        return;
    }
    if (blk < 168) {
        int g = blk - 24;              // 144 blocks: 12x12 tiles
        gemm_device<1>(QwbT, KwbT, Mt, g % 12, g / 12, 0,
                       Dn, Dn, Dn, Dn, 0, 0, 0, SB, SB + 8192);
        return;
    }
    if (blk == 680) {
        if (t >= 64) return;
        int l = t;
        double c0 = 0.0, c1 = 0.0, c2 = 0.0, c3 = 0.0;
        for (int e = l; e < Dn; e += 64) {
            c0 += kbar[e] * (double)Q_b[e];
            c1 += kbar[e] * qbar[e];
            c2 += qbar[e] * (double)K_b[e];
            c3 += (double)K_b[e] * (double)Q_b[e];
        }
        #pragma unroll
        for (int off = 32; off > 0; off >>= 1) {
            c0 += __shfl_down(c0, off, 64);
            c1 += __shfl_down(c1, off, 64);
            c2 += __shfl_down(c2, off, 64);
            c3 += __shfl_down(c3, off, 64);
        }
        if (l == 0) { consts[0] = c0; consts[1] = c1; consts[2] = c2; consts[3] = c3; }
        return;
    }
    int ab = blk - 168;                // 0..511
    int b = ab >> 5, rc = ab & 31;
    const float* base = adj + ((size_t)b * Sn + rc * 16) * Sn;
    float* obase = adjsm + ((size_t)b * Sn + rc * 16) * Sn;
    const float EM1 = 0.36787944117144233f;   // exp(-1)
    const float EP1 = 2.718281828459045f;     // exp(+1)
    float (*rows)[512] = (float(*)[512])SB;   // 16*512*4 = 32 KB
    // stage 16 rows (2 cols per thread)
    #pragma unroll
    for (int r = 0; r < 16; ++r) {
        rows[r][t]       = base[(size_t)r * Sn + t];
        rows[r][t + 256] = base[(size_t)r * Sn + t + 256];
    }
    __syncthreads();
    // per-wave rowsums: wave w handles rows 4w..4w+3 (exact integer sums)
    int wv = t >> 6, lane = t & 63;
    #pragma unroll
    for (int rr2 = 0; rr2 < 4; ++rr2) {
        int r = wv * 4 + rr2;
        float s = 0.f;
        #pragma unroll
        for (int c = 0; c < 8; ++c) s += rows[r][lane + c * 64];
        #pragma unroll
        for (int off = 32; off > 0; off >>= 1) s += __shfl_down(s, off, 64);
        if (lane == 0) {
            n1s[r] = s;
            rowsum[(size_t)b * Sn + rc * 16 + r] = s;
        }
    }
    __syncthreads();
    float colacc0 = 0.f, colacc1 = 0.f;
    #pragma unroll
    for (int r = 0; r < 16; ++r) {
        float a0 = rows[r][t], a1 = rows[r][t + 256];
        colacc0 += a0; colacc1 += a1;
        float n1 = n1s[r];
        float e1, e0;
        if (n1 > 0.f) { e1 = 1.f; e0 = EM1; } else { e1 = EP1; e0 = 1.f; }
        float inv = 1.f / (n1 * e1 + (512.f - n1) * e0);
        obase[(size_t)r * Sn + t]       = (a0 == 1.f ? e1 : e0) * inv;
        obase[(size_t)r * Sn + t + 256] = (a1 == 1.f ? e1 : e0) * inv;
    }
    atomicAdd(&colsum[(size_t)b * Sn + t], colacc0);
    atomicAdd(&colsum[(size_t)b * Sn + t + 256], colacc1);
}

// ---------------------------------------------------------------------------
// merged: blocks 0..8191 = g pool (+f64 dots); 8192..8319 main s1; 8320..8831 user s1
__global__ __launch_bounds__(192)
void pool_g_s1(const int* __restrict__ words, const int* __restrict__ masks,
               const int* __restrict__ main_idx, const int* __restrict__ mmask,
               const int* __restrict__ user_idx, const int* __restrict__ umask,
               const float* __restrict__ emb,
               const double* __restrict__ u, const double* __restrict__ v,
               const double* __restrict__ va, const double* __restrict__ vb,
               const double* __restrict__ consts,
               ushort* __restrict__ gbf, float* __restrict__ qs,
               float* __restrict__ kq, float* __restrict__ ga,
               float* __restrict__ gb, int* __restrict__ flags,
               float* __restrict__ partM, float* __restrict__ partU) {
    int blk = blockIdx.x;
    int t = threadIdx.x;
    if (blk >= Bn * Sn) {
        int s1 = blk - Bn * Sn;
        const int *irow, *mrow;
        float* dst;
        if (s1 < 128) {
            int bm = s1 >> 2, ch = s1 & 3;
            irow = main_idx + (size_t)bm * WMn + ch * 16;
            mrow = mmask + (size_t)bm * WMn + ch * 16;
            dst = partM + (size_t)s1 * Dn;
        } else {
            int bu = s1 - 128;
            irow = user_idx + (size_t)bu * WUn;
            mrow = umask + (size_t)bu * WUn;
            dst = partU + (size_t)bu * Dn;
        }
        float4 acc = make_float4(-INF_VAL, -INF_VAL, -INF_VAL, -INF_VAL);
        #pragma unroll
        for (int w = 0; w < 16; ++w) {
            if (mrow[w] != 0) continue;
            float4 x = ((const float4*)(emb + (size_t)irow[w] * Dn))[t];
            fmax4(acc, x);
        }
        ((float4*)dst)[t] = acc;
        return;
    }
    int bs = blk;
    const int* wrow = words + (size_t)bs * Wn;
    const int* mrow = masks + (size_t)bs * Wn;
    float4 acc = make_float4(-INF_VAL, -INF_VAL, -INF_VAL, -INF_VAL);
    int nm = 0;
    #pragma unroll
    for (int w = 0; w < Wn; ++w) {
        int mk = mrow[w];
        nm += (mk != 0);
        if (mk != 0) continue;
        float4 x = ((const float4*)(emb + (size_t)wrow[w] * Dn))[t];
        fmax4(acc, x);
    }
    ushort4 o;
    o.x = f2bf(acc.x); o.y = f2bf(acc.y); o.z = f2bf(acc.z); o.w = f2bf(acc.w);
    ((ushort4*)(gbf + (size_t)bs * Dn))[t] = o;
    int j = t * 4;
    double dv = v[j] * (double)acc.x + v[j+1] * (double)acc.y
              + v[j+2] * (double)acc.z + v[j+3] * (double)acc.w;
    double du = u[j] * (double)acc.x + u[j+1] * (double)acc.y
              + u[j+2] * (double)acc.z + u[j+3] * (double)acc.w;
    double da = va[j] * (double)acc.x + va[j+1] * (double)acc.y
              + va[j+2] * (double)acc.z + va[j+3] * (double)acc.w;
    double db = vb[j] * (double)acc.x + vb[j+1] * (double)acc.y
              + vb[j+2] * (double)acc.z + vb[j+3] * (double)acc.w;
    #pragma unroll
    for (int off = 32; off > 0; off >>= 1) {
        dv += __shfl_down(dv, off, 64);
        du += __shfl_down(du, off, 64);
        da += __shfl_down(da, off, 64);
        db += __shfl_down(db, off, 64);
    }
    __shared__ double rr[12];
    if ((t & 63) == 0) {
        rr[t >> 6] = dv; rr[3 + (t >> 6)] = du;
        rr[6 + (t >> 6)] = da; rr[9 + (t >> 6)] = db;
    }
    __syncthreads();
    if (t == 0) {
        qs[bs] = (float)(rr[0] + rr[1] + rr[2] + consts[0]);
        kq[bs] = (float)(rr[3] + rr[4] + rr[5] + consts[2]);
        ga[bs] = (float)(rr[6] + rr[7] + rr[8]);
        gb[bs] = (float)(rr[9] + rr[10] + rr[11]);
        flags[bs] = (nm == Wn) ? 1 : 0;
    }
}

// ---------------------------------------------------------------------------
// midh: blocks 0..1535 = h GEMM (critical path first); 1536..7679 transpose;
// 7680..7711 main s2; 7712..7727 user s2; 7728..7759 node mask.
__global__ __launch_bounds__(256)
void midh_kernel(const ushort* __restrict__ gbf, const ushort* __restrict__ Mt,
                 ushort* __restrict__ hbf, ushort* __restrict__ gT,
                 const float* __restrict__ partM, const float* __restrict__ partU,
                 float* __restrict__ outM, float* __restrict__ outU,
                 const float* __restrict__ rowsum, const float* __restrict__ colsum,
                 float* __restrict__ maskout) {
    __shared__ ushort SB[16384];       // 32 KB
    int blk = blockIdx.x;
    int t = threadIdx.x;
    if (blk < 1536) {
        gemm_device<1>(gbf, Mt, hbf, blk % 12, blk / 12, 0,
                       Dn, Dn, Dn, Dn, 0, 0, 0, SB, SB + 8192);
        return;
    }
    if (blk < 7680) {
        int bb = blk - 1536;
        ushort (*tile)[33] = (ushort(*)[33])SB;    // reuse GEMM LDS
        int b = bb / 384;
        int rem = bb - b * 384;
        int d0 = (rem % 24) * 32, s0 = (rem / 24) * 32;
        int tx = t & 31, ty = t >> 5;
        #pragma unroll
        for (int i = 0; i < 4; ++i)
            tile[ty + i * 8][tx] = gbf[((size_t)(b * Sn + s0 + ty + i * 8)) * Dn + d0 + tx];
        __syncthreads();
        #pragma unroll
        for (int i = 0; i < 4; ++i)
            gT[((size_t)(b * Dn + d0 + ty + i * 8)) * Sn + s0 + tx] = tile[tx][ty + i * 8];
        return;
    }
    if (blk >= 7728) {
        int i = (blk - 7728) * 256 + t;
        if (i < Bn * Sn)
            maskout[i] = ((rowsum[i] + colsum[i]) == 0.f) ? 1.f : 0.f;
        return;
    }
    if (t >= 192) return;
    float4 acc = make_float4(-INF_VAL, -INF_VAL, -INF_VAL, -INF_VAL);
    float* dst;
    if (blk < 7712) {
        int bm = blk - 7680;
        #pragma unroll
        for (int c = 0; c < 4; ++c) {
            float4 x = ((const float4*)(partM + (size_t)(bm * 4 + c) * Dn))[t];
            fmax4(acc, x);
        }
        dst = outM + (size_t)bm * Dn;
    } else {
        int b = blk - 7712;
        for (int u2 = 0; u2 < Un; ++u2) {
            float4 x = ((const float4*)(partU + (size_t)(b * Un + u2) * Dn))[t];
            fmax4(acc, x);
        }
        dst = outU + (size_t)b * Dn;
    }
    if (acc.x == -INF_VAL) acc.x = 0.f;
    if (acc.y == -INF_VAL) acc.y = 0.f;
    if (acc.z == -INF_VAL) acc.z = 0.f;
    if (acc.w == -INF_VAL) acc.w = 0.f;
    ((float4*)dst)[t] = acc;
}

// ---------------------------------------------------------------------------
// scores fixup + bias-rank1 correction + row softmax. Raw scores read as bf16
// (finite-only entries; masked rows/cols overridden by exact qs/kq path).
__global__ __launch_bounds__(256)
void softmax_fix(const ushort* __restrict__ raw, const int* __restrict__ flags,
                 const float* __restrict__ qs, const float* __restrict__ kq,
                 const float* __restrict__ ga, const float* __restrict__ gb,
                 const double* __restrict__ consts,
                 float* __restrict__ dense, ushort* __restrict__ densebf) {
    int bs = blockIdx.x;
    int b = bs >> 9;
    int t = threadIdx.x;
    int c0i = 2 * t, c1idx = 2 * t + 1;
    unsigned rpack = ((const unsigned*)(raw + (size_t)bs * 512))[t];
    float r0 = bf2f(rpack & 0xFFFFu);
    float r1 = bf2f(rpack >> 16);
    int f0 = flags[(b << 9) + c0i];
    int f1 = flags[(b << 9) + c1idx];
    bool sm = flags[bs] != 0;
    float x0, x1;
    if (sm) {
        float c1v = (float)consts[1] * INV_SQRT_D;
        x0 = f0 ? c1v : qs[(b << 9) + c0i] * INV_SQRT_D;
        x1 = f1 ? c1v : qs[(b << 9) + c1idx] * INV_SQRT_D;
    } else {
        float kqi = kq[bs] * INV_SQRT_D;
        float corr = ga[bs] + (float)consts[3];
        x0 = f0 ? kqi : (r0 + corr + gb[(b << 9) + c0i]) * INV_SQRT_D;
        x1 = f1 ? kqi : (r1 + corr + gb[(b << 9) + c1idx]) * INV_SQRT_D;
    }
    float m = fmaxf(x0, x1);
    #pragma unroll
    for (int off = 32; off > 0; off >>= 1) m = fmaxf(m, __shfl_down(m, off, 64));
    __shared__ float red[4];
    __shared__ float bmax, bsum;
    if ((t & 63) == 0) red[t >> 6] = m;
    __syncthreads();
    if (t == 0) bmax = fmaxf(fmaxf(red[0], red[1]), fmaxf(red[2], red[3]));
    __syncthreads();
    float mx = bmax;
    float e0 = expf(x0 - mx), e1 = expf(x1 - mx);
    float s = e0 + e1;
    #pragma unroll
    for (int off = 32; off > 0; off >>= 1) s += __shfl_down(s, off, 64);
    if ((t & 63) == 0) red[t >> 6] = s;
    __syncthreads();
    if (t == 0) bsum = red[0] + red[1] + red[2] + red[3];
    __syncthreads();
    float inv = 1.f / bsum;
    float p0 = e0 * inv, p1 = e1 * inv;
    float2 pv; pv.x = p0; pv.y = p1;
    ((float2*)(dense + (size_t)bs * 512))[t] = pv;
    ((unsigned*)(densebf + (size_t)bs * 512))[t] =
        (unsigned)f2bf(p0) | ((unsigned)f2bf(p1) << 16);
}

// ---------------------------------------------------------------------------
extern "C" void kernel_launch(void* const* d_in, const int* in_sizes, int n_in,
                              void* d_out, int out_size, void* d_ws, size_t ws_size,
                              hipStream_t stream) {
    const int*   words     = (const int*)d_in[0];
    const int*   masks     = (const int*)d_in[1];
    const int*   main_idx  = (const int*)d_in[2];
    const int*   main_mask = (const int*)d_in[3];
    const int*   user_idx  = (const int*)d_in[4];
    const int*   user_mask = (const int*)d_in[5];
    const float* adj       = (const float*)d_in[6];
    const float* emb       = (const float*)d_in[7];
    const float* K_w       = (const float*)d_in[8];
    const float* K_b       = (const float*)d_in[9];
    const float* Q_w       = (const float*)d_in[10];
    const float* Q_b       = (const float*)d_in[11];

    float* out = (float*)d_out;
    char*  ws8 = (char*)d_ws;

    ushort* gbf     = (ushort*)(ws8 + WSB_GBF);
    ushort* gT      = (ushort*)(ws8 + WSB_GT);
    ushort* densebf = (ushort*)(ws8 + WSB_DENSEBF);
    ushort* hbf     = (ushort*)(ws8 + WSB_HBF);
    ushort* KwbT    = (ushort*)(ws8 + WSB_KWT);
    ushort* QwbT    = (ushort*)(ws8 + WSB_QWT);
    ushort* Mt      = (ushort*)(ws8 + WSB_MT);
    ushort* rawbf   = (ushort*)(ws8 + WSB_RAWBF);
    float*  partU   = (float*)(ws8 + WSB_PARTU);
    float*  partM   = (float*)(ws8 + WSB_PARTM);
    double* kbar    = (double*)(ws8 + WSB_KBAR);
    double* qbar    = (double*)(ws8 + WSB_QBAR);
    double* u       = (double*)(ws8 + WSB_U);
    double* v       = (double*)(ws8 + WSB_V);
    double* va      = (double*)(ws8 + WSB_VA);
    double* vb      = (double*)(ws8 + WSB_VB);
    double* consts  = (double*)(ws8 + WSB_CONSTS);
    float*  qs      = (float*)(ws8 + WSB_QS);
    float*  kq      = (float*)(ws8 + WSB_KQ);
    float*  ga      = (float*)(ws8 + WSB_GA);
    float*  gb      = (float*)(ws8 + WSB_GB);
    float*  colsum  = (float*)(ws8 + WSB_COLSUM);
    int*    flags   = (int*)(ws8 + WSB_FLAGS);
    float*  rowsum  = (float*)(ws8 + WSB_ROWSUM);

    float* dense = out + OFF_DENSE;

    // 1: weight row-sums + transposed bf16 converts + zero colsum/u/v/va/vb
    fold1<<<1345, 256, 0, stream>>>(K_w, K_b, Q_w, Q_b, kbar, qbar, KwbT, QwbT,
                                    colsum, u /* u,v,va,vb contiguous */);

    // 2: u/v/a/b fold (f64 atomics) ∥ Mt GEMM ∥ adj softmax ∥ consts (merged)
    adjuvmt_kernel<<<681, 256, 0, stream>>>(adj, out + OFF_ADJ, colsum, rowsum,
                                            K_w, Q_w, K_b, Q_b, kbar, qbar,
                                            u, v, va, vb, consts, QwbT, KwbT, Mt);

    // 3: pools (g + s1 merged)
    pool_g_s1<<<Bn * Sn + 640, 192, 0, stream>>>(
        words, masks, main_idx, main_mask, user_idx, user_mask, emb,
        u, v, va, vb, consts, gbf, qs, kq, ga, gb, flags, partM, partU);

    // 4: h GEMM (1536 blocks) ∥ transpose g ∥ pool stage2 ∥ node mask (merged)
    midh_kernel<<<7760, 256, 0, stream>>>(gbf, Mt, hbf, gT, partM, partU,
                                          out + OFF_MAIN, out + OFF_USER,
                                          rowsum, colsum, out + OFF_MASK);

    // 5: raw scores[b] = h[b] @ g[b]^T -> bf16 (1024 blocks, 4/CU)
    gemm_mfma<1><<<dim3(8, 8, Bn), 256, 0, stream>>>(
        hbf, gbf, rawbf, Dn, Dn, Dn, Sn,
        (long long)Sn * Dn, (long long)Sn * Dn, (long long)Sn * Sn);

    // 6: fixup masked rows/cols + bias rank-1 + softmax (bf16 raw in)
    softmax_fix<<<Bn * Sn, 256, 0, stream>>>(rawbf, flags, qs, kq, ga, gb, consts,
                                             dense, densebf);

    // 7: gcn[b] = P[b] @ g[b]  (1536 blocks, 6/CU)
    gemm_mfma<0><<<dim3(12, 8, Bn), 256, 0, stream>>>(
        densebf, gT, out + OFF_GCN, Sn, Sn, Sn, Dn,
        (long long)Sn * Sn, (long long)Dn * Sn, (long long)Sn * Dn);
}